// Round 9
// baseline (308.274 us; speedup 1.0000x reference)
//
#include <hip/hip_runtime.h>

// Problem constants
#define Bn  4
#define Cn  128
#define CQn 64
#define Nn  4096

typedef _Float16 h8_t __attribute__((ext_vector_type(8)));
typedef float    f32x4 __attribute__((ext_vector_type(4)));
typedef unsigned int u32;
typedef u32      u32x2 __attribute__((ext_vector_type(2)));

// ws layout (halves):
//  Qh: [B][N][64]   offset 0        (1,048,576)
//  Kh: [B][N][64]   offset 1048576  (1,048,576)
//  Vt: [B][128][N]  offset 2097152  (2,097,152)   (V transposed: [C][N])

// ---------------------------------------------------------------------------
// Kernel 1: fused QKV projection (fp32 compute, f16 outputs in attn layouts)
// ---------------------------------------------------------------------------
__global__ __launch_bounds__(256) void qkv_proj(
    const float* __restrict__ x,
    const float* __restrict__ Wq, const float* __restrict__ bq,
    const float* __restrict__ Wk, const float* __restrict__ bk,
    const float* __restrict__ Wv, const float* __restrict__ bv,
    _Float16* __restrict__ Qh, _Float16* __restrict__ Kh, _Float16* __restrict__ Vt)
{
    const int ntile = blockIdx.x;
    const int otile = blockIdx.y;
    const int b     = blockIdx.z;
    const int tid   = threadIdx.x;
    const int nbase = ntile * 64;

    __shared__ float Ws[64][132];
    __shared__ float Xs[128][68];

    const float* Wsrc; const float* bsrc; int obase;
    if (otile == 0)      { Wsrc = Wq;                     bsrc = bq;      obase = 0; }
    else if (otile == 1) { Wsrc = Wk;                     bsrc = bk;      obase = 0; }
    else                 { Wsrc = Wv + (otile - 2) * 64 * Cn;
                           bsrc = bv + (otile - 2) * 64;  obase = (otile - 2) * 64; }

    for (int u = 0; u < 8; ++u) {
        int f = tid + u * 256;
        int row = f >> 5;
        int col = (f & 31) * 4;
        *(float4*)&Ws[row][col] = *(const float4*)&Wsrc[row * Cn + col];
    }
    const float* xb = x + ((size_t)b * Cn) * Nn + nbase;
    for (int u = 0; u < 8; ++u) {
        int f = tid + u * 256;
        int c = f >> 4;
        int n = (f & 15) * 4;
        *(float4*)&Xs[c][n] = *(const float4*)&xb[(size_t)c * Nn + n];
    }
    __syncthreads();

    const int o0 = (tid >> 4) * 4;
    const int n0 = (tid & 15) * 4;
    float acc[4][4] = {};

    for (int c = 0; c < Cn; c += 4) {
        float4 w4[4], x4[4];
        for (int oo = 0; oo < 4; ++oo) w4[oo] = *(const float4*)&Ws[o0 + oo][c];
        for (int cc = 0; cc < 4; ++cc) x4[cc] = *(const float4*)&Xs[c + cc][n0];
        for (int oo = 0; oo < 4; ++oo) {
            const float* wv = (const float*)&w4[oo];
            for (int cc = 0; cc < 4; ++cc) {
                const float wsv = wv[cc];
                const float* xp = (const float*)&x4[cc];
                acc[oo][0] += wsv * xp[0];
                acc[oo][1] += wsv * xp[1];
                acc[oo][2] += wsv * xp[2];
                acc[oo][3] += wsv * xp[3];
            }
        }
    }

    float bias[4];
    for (int oo = 0; oo < 4; ++oo) bias[oo] = bsrc[o0 + oo];

    union H4 { _Float16 e[4]; short4 v; };

    if (otile <= 1) {
        _Float16* dst = (otile == 0 ? Qh : Kh) + ((size_t)b * Nn + nbase) * CQn;
        for (int nn = 0; nn < 4; ++nn) {
            H4 h;
            for (int oo = 0; oo < 4; ++oo) h.e[oo] = (_Float16)(acc[oo][nn] + bias[oo]);
            *(short4*)&dst[(size_t)(n0 + nn) * CQn + o0] = h.v;
        }
    } else {
        _Float16* dst = Vt + (size_t)b * Cn * Nn;
        const int og = obase + o0;
        for (int oo = 0; oo < 4; ++oo) {
            H4 h;
            for (int nn = 0; nn < 4; ++nn) h.e[nn] = (_Float16)(acc[oo][nn] + bias[oo]);
            *(short4*)&dst[(size_t)(og + oo) * Nn + nbase + n0] = h.v;
        }
    }
}

// ---------------------------------------------------------------------------
// Kernel 2: barrier-free MFMA flash attention, 256 threads = 4 waves.
// Block = 16 queries (wib = blockIdx.x*16); wave s in 0..3 processes
// j-tiles [16s, 16s+16) independently -- NO per-tile barriers, no V LDS.
// Rationale (rounds 4-8): 1024-thread workgroups pin the allocator at
// 64 VGPRs (16 waves x 128 = whole CU pool refused) -> unavoidable spill;
// 256-thread kernels allocate freely (round 3: 112 VGPR, 0 spill).
// Occupancy now comes from the grid: 256 itiles x 4 b = 1024 blocks
// (~3-4 blocks/CU = 3-4 waves/SIMD).
// PV B-fragments gather directly from L2-resident Vt (1 MB/batch) by the
// same kappa(e,g)=4g+(e&3)+16*(e>>2) map used to place P into A-slots,
// so the contraction is correct for any HW k-slot map.
// Epilogue: 2-round LDS tree combine of (m,l,oacc) across the 4 splits.
// LDS = 16.6 KB combine scratch only.
// ---------------------------------------------------------------------------
__device__ __forceinline__ h8_t mkb(u32x2 lo, u32x2 hi) {
    union { h8_t h; u32 u[4]; } t;
    t.u[0] = lo[0]; t.u[1] = lo[1]; t.u[2] = hi[0]; t.u[3] = hi[1];
    return t.h;
}

__global__ __launch_bounds__(256) void attn_mfma(
    const _Float16* __restrict__ Qh, const _Float16* __restrict__ Kh,
    const _Float16* __restrict__ Vt, float* __restrict__ out)
{
    const int tid  = threadIdx.x;
    const int s    = tid >> 6;       // wave = kv split 0..3
    const int lane = tid & 63;
    const int g    = lane >> 4;
    const int ln   = lane & 15;
    const int b    = blockIdx.y;
    const int wib  = blockIdx.x * 16;

    __shared__ float comb[2][2048];  // 2 oacc slots (8 KB each)
    __shared__ float mlb[2][32];     // m,l per slot

    // Persistent Q fragments (B operand: col=ln -> query wib+ln)
    const _Float16* qrow = Qh + ((size_t)(b * Nn + wib + ln)) * CQn + 8 * g;
    const h8_t q0 = *(const h8_t*)(qrow);
    const h8_t q1 = *(const h8_t*)(qrow + 32);

    const _Float16* Kb  = Kh + (size_t)b * Nn * CQn;
    const _Float16* Vtb = Vt + (size_t)b * Cn * Nn;

    f32x4 oacc[8];
    #pragma unroll
    for (int i = 0; i < 8; ++i) oacc[i] = (f32x4){0.f, 0.f, 0.f, 0.f};
    float m_run = -3.0e38f, l_run = 0.f;

    for (int t = 0; t < 16; ++t) {
        const int jbase = (s * 16 + t) * 64;

        // 1) K fragments (8 x b128 gathers, L2-resident)
        h8_t kf[4][2];
        const _Float16* kbase = Kb + ((size_t)(jbase + ln)) * CQn + 8 * g;
        #pragma unroll
        for (int js = 0; js < 4; ++js) {
            kf[js][0] = *(const h8_t*)(kbase + js * 16 * CQn);
            kf[js][1] = *(const h8_t*)(kbase + js * 16 * CQn + 32);
        }

        // 2) scores: st[js] rows = keys js*16+4g+r, col = query ln
        f32x4 st[4];
        #pragma unroll
        for (int js = 0; js < 4; ++js) {
            st[js] = (f32x4){0.f, 0.f, 0.f, 0.f};
            st[js] = __builtin_amdgcn_mfma_f32_16x16x32_f16(kf[js][0], q0, st[js], 0, 0, 0);
            st[js] = __builtin_amdgcn_mfma_f32_16x16x32_f16(kf[js][1], q1, st[js], 0, 0, 0);
        }

        // 3) V fragments: issue now so ~L2 latency hides under softmax.
        //    vfrag[cs][p]: 4 f16 at Vt[cs*16+ln][jbase + 16p + 4g .. +3]
        //    = B-slots by the same kappa map as P below.
        u32x2 vfrag[8][4];
        #pragma unroll
        for (int cs = 0; cs < 8; ++cs) {
            const _Float16* vr = Vtb + (size_t)(cs * 16 + ln) * Nn + jbase + 4 * g;
            vfrag[cs][0] = *(const u32x2*)(vr);
            vfrag[cs][1] = *(const u32x2*)(vr + 16);
            vfrag[cs][2] = *(const u32x2*)(vr + 32);
            vfrag[cs][3] = *(const u32x2*)(vr + 48);
        }

        // 4) online softmax (per query = per ln, replicated over g)
        float tmax = st[0][0];
        #pragma unroll
        for (int js = 0; js < 4; ++js)
            #pragma unroll
            for (int r = 0; r < 4; ++r) tmax = fmaxf(tmax, st[js][r]);
        tmax = fmaxf(tmax, __shfl_xor(tmax, 16));
        tmax = fmaxf(tmax, __shfl_xor(tmax, 32));
        const float mnew = fmaxf(m_run, tmax);
        float ts = 0.f;
        #pragma unroll
        for (int js = 0; js < 4; ++js)
            #pragma unroll
            for (int r = 0; r < 4; ++r) {
                float p = __expf(st[js][r] - mnew);
                st[js][r] = p;
                ts += p;
            }
        ts += __shfl_xor(ts, 16);
        ts += __shfl_xor(ts, 32);
        const float alpha = __expf(m_run - mnew);
        l_run = l_run * alpha + ts;
        m_run = mnew;

        const float a0 = __shfl(alpha, 4 * g + 0);
        const float a1 = __shfl(alpha, 4 * g + 1);
        const float a2 = __shfl(alpha, 4 * g + 2);
        const float a3 = __shfl(alpha, 4 * g + 3);
        #pragma unroll
        for (int cs = 0; cs < 8; ++cs) {
            oacc[cs][0] *= a0; oacc[cs][1] *= a1;
            oacc[cs][2] *= a2; oacc[cs][3] *= a3;
        }

        // 5) P fragments by kappa(e,g) = 4g+(e&3)+16*(e>>2)
        union H8 { h8_t h; _Float16 e[8]; };
        H8 p0u, p1u;
        #pragma unroll
        for (int r = 0; r < 4; ++r) {
            p0u.e[r]     = (_Float16)st[0][r];
            p0u.e[4 + r] = (_Float16)st[1][r];
            p1u.e[r]     = (_Float16)st[2][r];
            p1u.e[4 + r] = (_Float16)st[3][r];
        }
        const h8_t pa0 = p0u.h;
        const h8_t pa1 = p1u.h;

        // 6) PV
        #pragma unroll
        for (int cs = 0; cs < 8; ++cs) {
            oacc[cs] = __builtin_amdgcn_mfma_f32_16x16x32_f16(pa0, mkb(vfrag[cs][0], vfrag[cs][1]), oacc[cs], 0, 0, 0);
            oacc[cs] = __builtin_amdgcn_mfma_f32_16x16x32_f16(pa1, mkb(vfrag[cs][2], vfrag[cs][3]), oacc[cs], 0, 0, 0);
        }
    }

    // ---- combine partials across the 4 split-waves (2-round tree) ----
    auto storeSlot = [&](int k) {
        #pragma unroll
        for (int cs = 0; cs < 8; ++cs)
            *(f32x4*)&comb[k][cs * 256 + lane * 4] = oacc[cs];
        if (g == 0) {
            mlb[k][ln]      = m_run;
            mlb[k][16 + ln] = l_run;
        }
    };
    auto mergeSlot = [&](int k) {
        const float mb = mlb[k][ln];
        const float lb = mlb[k][16 + ln];
        const float mn = fmaxf(m_run, mb);
        const float fa = __expf(m_run - mn);
        const float fb = __expf(mb - mn);
        l_run = fa * l_run + fb * lb;
        m_run = mn;
        const float fa0 = __shfl(fa, 4 * g + 0), fb0 = __shfl(fb, 4 * g + 0);
        const float fa1 = __shfl(fa, 4 * g + 1), fb1 = __shfl(fb, 4 * g + 1);
        const float fa2 = __shfl(fa, 4 * g + 2), fb2 = __shfl(fb, 4 * g + 2);
        const float fa3 = __shfl(fa, 4 * g + 3), fb3 = __shfl(fb, 4 * g + 3);
        #pragma unroll
        for (int cs = 0; cs < 8; ++cs) {
            f32x4 ob = *(const f32x4*)&comb[k][cs * 256 + lane * 4];
            oacc[cs][0] = fa0 * oacc[cs][0] + fb0 * ob[0];
            oacc[cs][1] = fa1 * oacc[cs][1] + fb1 * ob[1];
            oacc[cs][2] = fa2 * oacc[cs][2] + fb2 * ob[2];
            oacc[cs][3] = fa3 * oacc[cs][3] + fb3 * ob[3];
        }
    };

    if (s >= 2) storeSlot(s - 2);       // s2 -> slot0, s3 -> slot1
    __syncthreads();
    if (s < 2)  mergeSlot(s);           // s0 merges slot0, s1 merges slot1
    __syncthreads();
    if (s == 1) storeSlot(0);
    __syncthreads();
    if (s == 0) {
        mergeSlot(0);
        // Epilogue: out[b][c][i], rows i = wib+4g+r, col c = cs*16+ln
        const float lr = 1.f / l_run;
        const float l0 = __shfl(lr, 4 * g + 0);
        const float l1 = __shfl(lr, 4 * g + 1);
        const float l2 = __shfl(lr, 4 * g + 2);
        const float l3 = __shfl(lr, 4 * g + 3);
        float* ob = out + (size_t)b * Cn * Nn;
        #pragma unroll
        for (int cs = 0; cs < 8; ++cs) {
            float4 o;
            o.x = oacc[cs][0] * l0;
            o.y = oacc[cs][1] * l1;
            o.z = oacc[cs][2] * l2;
            o.w = oacc[cs][3] * l3;
            *(float4*)&ob[(size_t)(cs * 16 + ln) * Nn + wib + 4 * g] = o;
        }
    }
}

extern "C" void kernel_launch(void* const* d_in, const int* in_sizes, int n_in,
                              void* d_out, int out_size, void* d_ws, size_t ws_size,
                              hipStream_t stream) {
    const float* x  = (const float*)d_in[0];
    const float* Wq = (const float*)d_in[1];
    const float* bq = (const float*)d_in[2];
    const float* Wk = (const float*)d_in[3];
    const float* bk = (const float*)d_in[4];
    const float* Wv = (const float*)d_in[5];
    const float* bv = (const float*)d_in[6];
    float* out = (float*)d_out;

    _Float16* ws = (_Float16*)d_ws;
    _Float16* Qh = ws;
    _Float16* Kh = ws + 1048576;
    _Float16* Vt = ws + 2097152;

    dim3 gproj(Nn / 64, 4, Bn);
    qkv_proj<<<gproj, 256, 0, stream>>>(x, Wq, bq, Wk, bk, Wv, bv, Qh, Kh, Vt);

    dim3 gattn(Nn / 16, Bn);
    attn_mfma<<<gattn, 256, 0, stream>>>(Qh, Kh, Vt, out);
}

// Round 10
// 167.323 us; speedup vs baseline: 1.8424x; 1.8424x over previous
//
#include <hip/hip_runtime.h>

// Problem constants
#define Bn  4
#define Cn  128
#define CQn 64
#define Nn  4096

typedef _Float16 h8_t __attribute__((ext_vector_type(8)));
typedef float    f32x4 __attribute__((ext_vector_type(4)));
typedef unsigned int u32;
typedef u32      u32x2 __attribute__((ext_vector_type(2)));

// ws layout (bytes):
//  Qh: [B][N][64]  f16 at 0         (2 MB)
//  Kh: [B][N][64]  f16 at 2 MB      (2 MB)
//  Vt: [B][128][N] f16 at 4 MB      (4 MB)
//  pPart: [B][64 it][S][128 c][64 q] f32 at 8 MB   (S x 8 MB)
//  pMl:   [B][64 it][S][64 q][2]    f32 after      (S x 128 KB)

#define QKV_BYTES   8388608ull
#define PART_PER_S  8388608ull
#define ML_PER_S    131072ull

// ---------------------------------------------------------------------------
// Kernel 1: fused QKV projection (fp32 compute, f16 outputs in attn layouts)
// ---------------------------------------------------------------------------
__global__ __launch_bounds__(256) void qkv_proj(
    const float* __restrict__ x,
    const float* __restrict__ Wq, const float* __restrict__ bq,
    const float* __restrict__ Wk, const float* __restrict__ bk,
    const float* __restrict__ Wv, const float* __restrict__ bv,
    _Float16* __restrict__ Qh, _Float16* __restrict__ Kh, _Float16* __restrict__ Vt)
{
    const int ntile = blockIdx.x;
    const int otile = blockIdx.y;
    const int b     = blockIdx.z;
    const int tid   = threadIdx.x;
    const int nbase = ntile * 64;

    __shared__ float Ws[64][132];
    __shared__ float Xs[128][68];

    const float* Wsrc; const float* bsrc; int obase;
    if (otile == 0)      { Wsrc = Wq;                     bsrc = bq;      obase = 0; }
    else if (otile == 1) { Wsrc = Wk;                     bsrc = bk;      obase = 0; }
    else                 { Wsrc = Wv + (otile - 2) * 64 * Cn;
                           bsrc = bv + (otile - 2) * 64;  obase = (otile - 2) * 64; }

    for (int u = 0; u < 8; ++u) {
        int f = tid + u * 256;
        int row = f >> 5;
        int col = (f & 31) * 4;
        *(float4*)&Ws[row][col] = *(const float4*)&Wsrc[row * Cn + col];
    }
    const float* xb = x + ((size_t)b * Cn) * Nn + nbase;
    for (int u = 0; u < 8; ++u) {
        int f = tid + u * 256;
        int c = f >> 4;
        int n = (f & 15) * 4;
        *(float4*)&Xs[c][n] = *(const float4*)&xb[(size_t)c * Nn + n];
    }
    __syncthreads();

    const int o0 = (tid >> 4) * 4;
    const int n0 = (tid & 15) * 4;
    float acc[4][4] = {};

    for (int c = 0; c < Cn; c += 4) {
        float4 w4[4], x4[4];
        for (int oo = 0; oo < 4; ++oo) w4[oo] = *(const float4*)&Ws[o0 + oo][c];
        for (int cc = 0; cc < 4; ++cc) x4[cc] = *(const float4*)&Xs[c + cc][n0];
        for (int oo = 0; oo < 4; ++oo) {
            const float* wv = (const float*)&w4[oo];
            for (int cc = 0; cc < 4; ++cc) {
                const float wsv = wv[cc];
                const float* xp = (const float*)&x4[cc];
                acc[oo][0] += wsv * xp[0];
                acc[oo][1] += wsv * xp[1];
                acc[oo][2] += wsv * xp[2];
                acc[oo][3] += wsv * xp[3];
            }
        }
    }

    float bias[4];
    for (int oo = 0; oo < 4; ++oo) bias[oo] = bsrc[o0 + oo];

    union H4 { _Float16 e[4]; short4 v; };

    if (otile <= 1) {
        _Float16* dst = (otile == 0 ? Qh : Kh) + ((size_t)b * Nn + nbase) * CQn;
        for (int nn = 0; nn < 4; ++nn) {
            H4 h;
            for (int oo = 0; oo < 4; ++oo) h.e[oo] = (_Float16)(acc[oo][nn] + bias[oo]);
            *(short4*)&dst[(size_t)(n0 + nn) * CQn + o0] = h.v;
        }
    } else {
        _Float16* dst = Vt + (size_t)b * Cn * Nn;
        const int og = obase + o0;
        for (int oo = 0; oo < 4; ++oo) {
            H4 h;
            for (int nn = 0; nn < 4; ++nn) h.e[nn] = (_Float16)(acc[oo][nn] + bias[oo]);
            *(short4*)&dst[(size_t)(og + oo) * Nn + nbase + n0] = h.v;
        }
    }
}

// ---------------------------------------------------------------------------
// Kernel 2: round-3's proven MFMA flash attention, with KV split across
// BLOCKS (grid z = split s; each block does 64/S j-tiles). Round-9 lesson:
// V must be staged through LDS with coalesced 16B loads (direct gathers
// touch 16 cache lines per instr -> VMEM wall). Round-3 lesson: this body
// (17 KB LDS, ~112 VGPR, 256 thr) fits 4 blocks/CU -- the 162 us was grid
// starvation (256 blocks = 1/CU). S=4 -> 1024 blocks -> 4/CU.
// When S>1, each block writes flash partials (oacc[c][q], m, l) to ws;
// attn_combine merges. When S==1, writes out directly (ws-size fallback).
// ---------------------------------------------------------------------------
__device__ __forceinline__ h8_t mkb(u32x2 lo, u32x2 hi) {
    union { h8_t h; u32 u[4]; } t;
    t.u[0] = lo[0]; t.u[1] = lo[1]; t.u[2] = hi[0]; t.u[3] = hi[1];
    return t.h;
}

__global__ __launch_bounds__(256) void attn_split(
    const _Float16* __restrict__ Qh, const _Float16* __restrict__ Kh,
    const _Float16* __restrict__ Vt, float* __restrict__ out,
    float* __restrict__ pPart, float* __restrict__ pMl, int S)
{
    const int tid  = threadIdx.x;
    const int w    = tid >> 6;
    const int lane = tid & 63;
    const int g    = lane >> 4;
    const int ln   = lane & 15;
    const int it   = blockIdx.x;
    const int b    = blockIdx.y;
    const int s    = blockIdx.z;
    const int wib  = it * 64 + w * 16;
    const int njt  = 64 / S;

    __shared__ _Float16 Vs[128][68];   // [c][j], 136B stride

    const _Float16* qrow = Qh + ((size_t)(b * Nn + wib + ln)) * CQn + 8 * g;
    const h8_t q0 = *(const h8_t*)(qrow);
    const h8_t q1 = *(const h8_t*)(qrow + 32);

    const _Float16* Kb  = Kh + (size_t)b * Nn * CQn;
    const _Float16* Vtb = Vt + (size_t)b * Cn * Nn;

    f32x4 oacc[8];
    #pragma unroll
    for (int i = 0; i < 8; ++i) oacc[i] = (f32x4){0.f, 0.f, 0.f, 0.f};
    float m_run = -3.0e38f, l_run = 0.f;

    for (int t = 0; t < njt; ++t) {
        const int jbase = (s * njt + t) * 64;

        // 1) K fragments (direct gathers, L2-resident; 16B/lane)
        h8_t kf[4][2];
        const _Float16* kbase = Kb + ((size_t)(jbase + ln)) * CQn + 8 * g;
        #pragma unroll
        for (int js = 0; js < 4; ++js) {
            kf[js][0] = *(const h8_t*)(kbase + js * 16 * CQn);
            kf[js][1] = *(const h8_t*)(kbase + js * 16 * CQn + 32);
        }

        // 2) V-stage global loads, coalesced (complete under scores+softmax)
        float4 vr[4];
        const _Float16* vg = Vtb + jbase;
        #pragma unroll
        for (int u = 0; u < 4; ++u) {
            int f = tid + u * 256;
            vr[u] = *(const float4*)(vg + (size_t)(f >> 3) * Nn + (f & 7) * 8);
        }

        // 3) scores: st[js] rows = keys js*16+4g+r, col = query ln
        f32x4 st[4];
        #pragma unroll
        for (int js = 0; js < 4; ++js) {
            st[js] = (f32x4){0.f, 0.f, 0.f, 0.f};
            st[js] = __builtin_amdgcn_mfma_f32_16x16x32_f16(kf[js][0], q0, st[js], 0, 0, 0);
            st[js] = __builtin_amdgcn_mfma_f32_16x16x32_f16(kf[js][1], q1, st[js], 0, 0, 0);
        }

        // 4) online softmax (per query = per ln, replicated over g)
        float tmax = st[0][0];
        #pragma unroll
        for (int js = 0; js < 4; ++js)
            #pragma unroll
            for (int r = 0; r < 4; ++r) tmax = fmaxf(tmax, st[js][r]);
        tmax = fmaxf(tmax, __shfl_xor(tmax, 16));
        tmax = fmaxf(tmax, __shfl_xor(tmax, 32));
        const float mnew = fmaxf(m_run, tmax);
        float ts = 0.f;
        #pragma unroll
        for (int js = 0; js < 4; ++js)
            #pragma unroll
            for (int r = 0; r < 4; ++r) {
                float p = __expf(st[js][r] - mnew);
                st[js][r] = p;
                ts += p;
            }
        ts += __shfl_xor(ts, 16);
        ts += __shfl_xor(ts, 32);
        const float alpha = __expf(m_run - mnew);
        l_run = l_run * alpha + ts;
        m_run = mnew;

        const float a0 = __shfl(alpha, 4 * g + 0);
        const float a1 = __shfl(alpha, 4 * g + 1);
        const float a2 = __shfl(alpha, 4 * g + 2);
        const float a3 = __shfl(alpha, 4 * g + 3);
        #pragma unroll
        for (int cs = 0; cs < 8; ++cs) {
            oacc[cs][0] *= a0; oacc[cs][1] *= a1;
            oacc[cs][2] *= a2; oacc[cs][3] *= a3;
        }

        // 5) P fragments by kappa(e,g) = 4g+(e&3)+16*(e>>2)
        union H8 { h8_t h; _Float16 e[8]; };
        H8 p0u, p1u;
        #pragma unroll
        for (int r = 0; r < 4; ++r) {
            p0u.e[r]     = (_Float16)st[0][r];
            p0u.e[4 + r] = (_Float16)st[1][r];
            p1u.e[r]     = (_Float16)st[2][r];
            p1u.e[4 + r] = (_Float16)st[3][r];
        }
        const h8_t pa0 = p0u.h;
        const h8_t pa1 = p1u.h;

        // 6) stage V tile into LDS
        __syncthreads();
        #pragma unroll
        for (int u = 0; u < 4; ++u) {
            int f = tid + u * 256;
            *(float4*)&Vs[f >> 3][(f & 7) * 8] = vr[u];
        }
        __syncthreads();

        // 7) PV: per c-subtile, gather B-fragments by the same kappa map
        #pragma unroll
        for (int cs = 0; cs < 8; ++cs) {
            const _Float16* vrow = &Vs[cs * 16 + ln][0];
            u32x2 a0v = *(const u32x2*)(vrow + 4 * g);
            u32x2 a1v = *(const u32x2*)(vrow + 4 * g + 16);
            u32x2 b0v = *(const u32x2*)(vrow + 4 * g + 32);
            u32x2 b1v = *(const u32x2*)(vrow + 4 * g + 48);
            oacc[cs] = __builtin_amdgcn_mfma_f32_16x16x32_f16(pa0, mkb(a0v, a1v), oacc[cs], 0, 0, 0);
            oacc[cs] = __builtin_amdgcn_mfma_f32_16x16x32_f16(pa1, mkb(b0v, b1v), oacc[cs], 0, 0, 0);
        }
    }

    if (S == 1) {
        // direct epilogue: out[b][c][i], rows i = wib+4g+r, col c = cs*16+ln
        const float lr = 1.f / l_run;
        const float l0 = __shfl(lr, 4 * g + 0);
        const float l1 = __shfl(lr, 4 * g + 1);
        const float l2 = __shfl(lr, 4 * g + 2);
        const float l3 = __shfl(lr, 4 * g + 3);
        float* ob = out + (size_t)b * Cn * Nn;
        #pragma unroll
        for (int cs = 0; cs < 8; ++cs) {
            float4 o;
            o.x = oacc[cs][0] * l0;
            o.y = oacc[cs][1] * l1;
            o.z = oacc[cs][2] * l2;
            o.w = oacc[cs][3] * l3;
            *(float4*)&ob[(size_t)(cs * 16 + ln) * Nn + wib + 4 * g] = o;
        }
    } else {
        // partial epilogue: pPart[(b,it,s)][c][64 q] (+ m,l per q)
        float* pp = pPart + (((size_t)b * 64 + it) * S + s) * 8192;
        const int qloc = w * 16 + 4 * g;
        #pragma unroll
        for (int cs = 0; cs < 8; ++cs)
            *(float4*)&pp[(size_t)(cs * 16 + ln) * 64 + qloc] =
                make_float4(oacc[cs][0], oacc[cs][1], oacc[cs][2], oacc[cs][3]);
        if (g == 0) {
            float* ml = pMl + ((((size_t)b * 64 + it) * S + s) * 64 + w * 16 + ln) * 2;
            ml[0] = m_run;
            ml[1] = l_run;
        }
    }
}

// ---------------------------------------------------------------------------
// Kernel 3: flash-combine across S splits. Grid (64 it, B), 256 threads.
// Thread t: c = t>>1, 32 queries (t&1 half). Contiguous 128B reads/writes.
// ---------------------------------------------------------------------------
__global__ __launch_bounds__(256) void attn_combine(
    const float* __restrict__ pPart, const float* __restrict__ pMl,
    float* __restrict__ out, int S)
{
    const int it  = blockIdx.x;
    const int b   = blockIdx.y;
    const int tid = threadIdx.x;

    __shared__ float wgt[4][64];
    __shared__ float linv[64];

    if (tid < 64) {
        const float* mlb = pMl + (((size_t)b * 64 + it) * S * 64 + tid) * 2;
        float ms[4], ls[4], m = -3.0e38f;
        for (int s = 0; s < S; ++s) {
            ms[s] = mlb[s * 128 + 0];
            ls[s] = mlb[s * 128 + 1];
            m = fmaxf(m, ms[s]);
        }
        float l = 0.f;
        for (int s = 0; s < S; ++s) {
            float wv = __expf(ms[s] - m);
            wgt[s][tid] = wv;
            l += wv * ls[s];
        }
        linv[tid] = 1.f / l;
    }
    __syncthreads();

    const int c  = tid >> 1;
    const int q0 = (tid & 1) * 32;
    const float* base = pPart + ((size_t)b * 64 + it) * S * 8192 + (size_t)c * 64 + q0;

    float acc[32];
    #pragma unroll
    for (int k = 0; k < 32; ++k) acc[k] = 0.f;
    for (int s = 0; s < S; ++s) {
        const float* ps = base + (size_t)s * 8192;
        #pragma unroll
        for (int k = 0; k < 32; k += 4) {
            float4 v = *(const float4*)(ps + k);
            acc[k + 0] += wgt[s][q0 + k + 0] * v.x;
            acc[k + 1] += wgt[s][q0 + k + 1] * v.y;
            acc[k + 2] += wgt[s][q0 + k + 2] * v.z;
            acc[k + 3] += wgt[s][q0 + k + 3] * v.w;
        }
    }
    float* ob = out + ((size_t)b * Cn + c) * Nn + it * 64 + q0;
    #pragma unroll
    for (int k = 0; k < 32; k += 4) {
        float4 o;
        o.x = acc[k + 0] * linv[q0 + k + 0];
        o.y = acc[k + 1] * linv[q0 + k + 1];
        o.z = acc[k + 2] * linv[q0 + k + 2];
        o.w = acc[k + 3] * linv[q0 + k + 3];
        *(float4*)&ob[k] = o;
    }
}

extern "C" void kernel_launch(void* const* d_in, const int* in_sizes, int n_in,
                              void* d_out, int out_size, void* d_ws, size_t ws_size,
                              hipStream_t stream) {
    const float* x  = (const float*)d_in[0];
    const float* Wq = (const float*)d_in[1];
    const float* bq = (const float*)d_in[2];
    const float* Wk = (const float*)d_in[3];
    const float* bk = (const float*)d_in[4];
    const float* Wv = (const float*)d_in[5];
    const float* bv = (const float*)d_in[6];
    float* out = (float*)d_out;

    _Float16* ws = (_Float16*)d_ws;
    _Float16* Qh = ws;
    _Float16* Kh = ws + 1048576;
    _Float16* Vt = ws + 2097152;

    // pick split factor from available ws (deterministic per environment)
    int S = 1;
    if (ws_size >= QKV_BYTES + 4 * (PART_PER_S + ML_PER_S)) S = 4;
    else if (ws_size >= QKV_BYTES + 2 * (PART_PER_S + ML_PER_S)) S = 2;

    float* pPart = (float*)((char*)d_ws + QKV_BYTES);
    float* pMl   = (float*)((char*)d_ws + QKV_BYTES + (size_t)S * PART_PER_S);

    dim3 gproj(Nn / 64, 4, Bn);
    qkv_proj<<<gproj, 256, 0, stream>>>(x, Wq, bq, Wk, bk, Wv, bv, Qh, Kh, Vt);

    dim3 gattn(Nn / 64, Bn, S);
    attn_split<<<gattn, 256, 0, stream>>>(Qh, Kh, Vt, out, pPart, pMl, S);

    if (S > 1) {
        dim3 gcomb(Nn / 64, Bn);
        attn_combine<<<gcomb, 256, 0, stream>>>(pPart, pMl, out, S);
    }
}

// Round 11
// 103.827 us; speedup vs baseline: 2.9691x; 1.6116x over previous
//
#include <hip/hip_runtime.h>

// Problem constants
#define Bn  4
#define Cn  128
#define CQn 64
#define Nn  4096

typedef _Float16 h8_t __attribute__((ext_vector_type(8)));
typedef float    f32x4 __attribute__((ext_vector_type(4)));
typedef unsigned int u32;
typedef u32      u32x2 __attribute__((ext_vector_type(2)));

// ws layout (bytes):
//  Qh: [B][N][64]  f16 at 0         (2 MB)
//  Kh: [B][N][64]  f16 at 2 MB      (2 MB)
//  Vt: [B][128][N] f16 at 4 MB      (4 MB)
//  pPart: [B][64 it][S][128 c][64 q] f32 at 8 MB   (S x 8 MB)
//  pMl:   [B][64 it][S][64 q][2]    f32 after      (S x 128 KB)

#define QKV_BYTES   8388608ull
#define PART_PER_S  8388608ull
#define ML_PER_S    131072ull

// ---------------------------------------------------------------------------
// Kernel 1: fused QKV projection (fp32 compute, f16 outputs in attn layouts)
// ---------------------------------------------------------------------------
__global__ __launch_bounds__(256) void qkv_proj(
    const float* __restrict__ x,
    const float* __restrict__ Wq, const float* __restrict__ bq,
    const float* __restrict__ Wk, const float* __restrict__ bk,
    const float* __restrict__ Wv, const float* __restrict__ bv,
    _Float16* __restrict__ Qh, _Float16* __restrict__ Kh, _Float16* __restrict__ Vt)
{
    const int ntile = blockIdx.x;
    const int otile = blockIdx.y;
    const int b     = blockIdx.z;
    const int tid   = threadIdx.x;
    const int nbase = ntile * 64;

    __shared__ float Ws[64][132];
    __shared__ float Xs[128][68];

    const float* Wsrc; const float* bsrc; int obase;
    if (otile == 0)      { Wsrc = Wq;                     bsrc = bq;      obase = 0; }
    else if (otile == 1) { Wsrc = Wk;                     bsrc = bk;      obase = 0; }
    else                 { Wsrc = Wv + (otile - 2) * 64 * Cn;
                           bsrc = bv + (otile - 2) * 64;  obase = (otile - 2) * 64; }

    for (int u = 0; u < 8; ++u) {
        int f = tid + u * 256;
        int row = f >> 5;
        int col = (f & 31) * 4;
        *(float4*)&Ws[row][col] = *(const float4*)&Wsrc[row * Cn + col];
    }
    const float* xb = x + ((size_t)b * Cn) * Nn + nbase;
    for (int u = 0; u < 8; ++u) {
        int f = tid + u * 256;
        int c = f >> 4;
        int n = (f & 15) * 4;
        *(float4*)&Xs[c][n] = *(const float4*)&xb[(size_t)c * Nn + n];
    }
    __syncthreads();

    const int o0 = (tid >> 4) * 4;
    const int n0 = (tid & 15) * 4;
    float acc[4][4] = {};

    for (int c = 0; c < Cn; c += 4) {
        float4 w4[4], x4[4];
        for (int oo = 0; oo < 4; ++oo) w4[oo] = *(const float4*)&Ws[o0 + oo][c];
        for (int cc = 0; cc < 4; ++cc) x4[cc] = *(const float4*)&Xs[c + cc][n0];
        for (int oo = 0; oo < 4; ++oo) {
            const float* wv = (const float*)&w4[oo];
            for (int cc = 0; cc < 4; ++cc) {
                const float wsv = wv[cc];
                const float* xp = (const float*)&x4[cc];
                acc[oo][0] += wsv * xp[0];
                acc[oo][1] += wsv * xp[1];
                acc[oo][2] += wsv * xp[2];
                acc[oo][3] += wsv * xp[3];
            }
        }
    }

    float bias[4];
    for (int oo = 0; oo < 4; ++oo) bias[oo] = bsrc[o0 + oo];

    union H4 { _Float16 e[4]; short4 v; };

    if (otile <= 1) {
        _Float16* dst = (otile == 0 ? Qh : Kh) + ((size_t)b * Nn + nbase) * CQn;
        for (int nn = 0; nn < 4; ++nn) {
            H4 h;
            for (int oo = 0; oo < 4; ++oo) h.e[oo] = (_Float16)(acc[oo][nn] + bias[oo]);
            *(short4*)&dst[(size_t)(n0 + nn) * CQn + o0] = h.v;
        }
    } else {
        _Float16* dst = Vt + (size_t)b * Cn * Nn;
        const int og = obase + o0;
        for (int oo = 0; oo < 4; ++oo) {
            H4 h;
            for (int nn = 0; nn < 4; ++nn) h.e[nn] = (_Float16)(acc[oo][nn] + bias[oo]);
            *(short4*)&dst[(size_t)(og + oo) * Nn + nbase + n0] = h.v;
        }
    }
}

// ---------------------------------------------------------------------------
// Kernel 2: MFMA flash attention, KV split across blocks (grid z = s).
// Round-10 post-mortem: ~38 MB/dispatch scratch traffic (FETCH/WRITE excess)
// = register spill in the hot loop; grid TLP bought nothing. This version
// cuts peak live regs (~130 -> ~100) by staging BOTH K (8 KB) and V (16 KB)
// tiles through double-buffered LDS via global_load_lds (async, 16B/lane),
// with the XOR swizzle sigma(byte) = byte ^ ((row&7)<<4) applied on the
// global SOURCE addresses (gload_lds writes linearly) and on every LDS read
// (unpadded 128B rows stay <=2-way conflict-free).
// 2-phase pipeline: stage tile t+1 into the other buffer BEFORE computing
// tile t; one __syncthreads per tile drains vmcnt after compute covered it.
// Swapped QK^T (D = S^T, col=query=ln); PV pairs P and V through the same
// kappa(e,g)=4g+(e&3)+16*(e>>2) slot map (correct for any HW k-map).
// Defer-max (THR=8): skip alpha/rescale when no query's max grew by >8.
// ---------------------------------------------------------------------------
__device__ __forceinline__ h8_t mkb(u32x2 lo, u32x2 hi) {
    union { h8_t h; u32 u[4]; } t;
    t.u[0] = lo[0]; t.u[1] = lo[1]; t.u[2] = hi[0]; t.u[3] = hi[1];
    return t.h;
}

__device__ __forceinline__ void gload16(const void* g, void* l) {
    __builtin_amdgcn_global_load_lds(
        (const __attribute__((address_space(1))) u32*)g,
        (__attribute__((address_space(3))) u32*)l, 16, 0, 0);
}

#define KOFF0 0
#define KOFF1 8192
#define VOFF0 16384
#define VOFF1 32768

__global__ __launch_bounds__(256) void attn_split(
    const _Float16* __restrict__ Qh, const _Float16* __restrict__ Kh,
    const _Float16* __restrict__ Vt, float* __restrict__ out,
    float* __restrict__ pPart, float* __restrict__ pMl, int S)
{
    __shared__ __align__(16) char smem[49152];

    const int tid  = threadIdx.x;
    const int w    = tid >> 6;
    const int lane = tid & 63;
    const int g    = lane >> 4;
    const int ln   = lane & 15;
    const int it   = blockIdx.x;
    const int b    = blockIdx.y;
    const int s    = blockIdx.z;
    const int wib  = it * 64 + w * 16;
    const int njt  = 64 / S;

    // Persistent Q fragments (B operand: col=ln -> query wib+ln)
    const _Float16* qrow = Qh + ((size_t)(b * Nn + wib + ln)) * CQn + 8 * g;
    const h8_t q0 = *(const h8_t*)(qrow);
    const h8_t q1 = *(const h8_t*)(qrow + 32);

    const _Float16* Kb  = Kh + (size_t)b * Nn * CQn;
    const _Float16* Vtb = Vt + (size_t)b * Cn * Nn;

    // --- staging source offsets (f16 units), swizzled per-lane ---
    int ks[2], vs[4];
    #pragma unroll
    for (int u = 0; u < 2; ++u) {
        int s16 = u * 256 + tid;
        int row = s16 >> 3;
        ks[u] = row * CQn + (((s16 & 7) ^ (row & 7)) * 8);
    }
    #pragma unroll
    for (int u = 0; u < 4; ++u) {
        int s16 = u * 256 + tid;
        int row = s16 >> 3;
        vs[u] = row * Nn + (((s16 & 7) ^ (row & 7)) * 8);
    }

    // --- LDS read offsets (bytes), swizzled per-lane ---
    const int r7  = ln & 7;
    const int kb0 = ln * 128 + ((g ^ r7) << 4);
    const int kb1 = ln * 128 + (((4 + g) ^ r7) << 4);
    int vb[4];
    #pragma unroll
    for (int p = 0; p < 4; ++p)
        vb[p] = ln * 128 + ((((g >> 1) + 2 * p) ^ r7) << 4) + (g & 1) * 8;

    auto stage = [&](int koff, int voff, int jt) {
        const _Float16* ksrc = Kb + (size_t)jt * 64 * CQn;
        #pragma unroll
        for (int u = 0; u < 2; ++u)
            gload16(ksrc + ks[u], smem + koff + u * 4096 + w * 1024);
        const _Float16* vsrc = Vtb + jt * 64;
        #pragma unroll
        for (int u = 0; u < 4; ++u)
            gload16(vsrc + vs[u], smem + voff + u * 4096 + w * 1024);
    };

    f32x4 oacc[8];
    #pragma unroll
    for (int i = 0; i < 8; ++i) oacc[i] = (f32x4){0.f, 0.f, 0.f, 0.f};
    float m_run = -3.0e38f, l_run = 0.f;

    const int jt0 = s * njt;
    stage(KOFF0, VOFF0, jt0);
    __syncthreads();

    for (int t = 0; t < njt; ++t) {
        const int ub = t & 1;
        if (t + 1 < njt)
            stage(ub ? KOFF0 : KOFF1, ub ? VOFF0 : VOFF1, jt0 + t + 1);

        const char* KU = smem + (ub ? KOFF1 : KOFF0);
        const char* VU = smem + (ub ? VOFF1 : VOFF0);

        // scores: st[js] rows = keys js*16+4g+r, col = query ln
        f32x4 st[4];
        __builtin_amdgcn_s_setprio(1);
        #pragma unroll
        for (int js = 0; js < 4; ++js) {
            h8_t k0 = *(const h8_t*)(KU + kb0 + js * 2048);
            h8_t k1 = *(const h8_t*)(KU + kb1 + js * 2048);
            st[js] = (f32x4){0.f, 0.f, 0.f, 0.f};
            st[js] = __builtin_amdgcn_mfma_f32_16x16x32_f16(k0, q0, st[js], 0, 0, 0);
            st[js] = __builtin_amdgcn_mfma_f32_16x16x32_f16(k1, q1, st[js], 0, 0, 0);
        }
        __builtin_amdgcn_s_setprio(0);

        // online softmax with defer-max (THR=8)
        float tmax = st[0][0];
        #pragma unroll
        for (int js = 0; js < 4; ++js)
            #pragma unroll
            for (int r = 0; r < 4; ++r) tmax = fmaxf(tmax, st[js][r]);
        tmax = fmaxf(tmax, __shfl_xor(tmax, 16));
        tmax = fmaxf(tmax, __shfl_xor(tmax, 32));
        if (__any(tmax > m_run + 8.f)) {
            const float mnew  = fmaxf(m_run, tmax);
            const float alpha = __expf(m_run - mnew);
            const float a0 = __shfl(alpha, 4 * g + 0);
            const float a1 = __shfl(alpha, 4 * g + 1);
            const float a2 = __shfl(alpha, 4 * g + 2);
            const float a3 = __shfl(alpha, 4 * g + 3);
            #pragma unroll
            for (int cs = 0; cs < 8; ++cs) {
                oacc[cs][0] *= a0; oacc[cs][1] *= a1;
                oacc[cs][2] *= a2; oacc[cs][3] *= a3;
            }
            l_run *= alpha;
            m_run = mnew;
        }
        float ts = 0.f;
        #pragma unroll
        for (int js = 0; js < 4; ++js)
            #pragma unroll
            for (int r = 0; r < 4; ++r) {
                float p = __expf(st[js][r] - m_run);
                st[js][r] = p;
                ts += p;
            }
        ts += __shfl_xor(ts, 16);
        ts += __shfl_xor(ts, 32);
        l_run += ts;

        // P fragments by kappa(e,g) = 4g+(e&3)+16*(e>>2)
        union H8 { h8_t h; _Float16 e[8]; };
        H8 p0u, p1u;
        #pragma unroll
        for (int r = 0; r < 4; ++r) {
            p0u.e[r]     = (_Float16)st[0][r];
            p0u.e[4 + r] = (_Float16)st[1][r];
            p1u.e[r]     = (_Float16)st[2][r];
            p1u.e[4 + r] = (_Float16)st[3][r];
        }
        const h8_t pa0 = p0u.h;
        const h8_t pa1 = p1u.h;

        // PV: per c-subtile, B fragments from swizzled V LDS by same kappa
        __builtin_amdgcn_s_setprio(1);
        #pragma unroll
        for (int cs = 0; cs < 8; ++cs) {
            u32x2 v0 = *(const u32x2*)(VU + vb[0] + cs * 2048);
            u32x2 v1 = *(const u32x2*)(VU + vb[1] + cs * 2048);
            u32x2 v2 = *(const u32x2*)(VU + vb[2] + cs * 2048);
            u32x2 v3 = *(const u32x2*)(VU + vb[3] + cs * 2048);
            oacc[cs] = __builtin_amdgcn_mfma_f32_16x16x32_f16(pa0, mkb(v0, v1), oacc[cs], 0, 0, 0);
            oacc[cs] = __builtin_amdgcn_mfma_f32_16x16x32_f16(pa1, mkb(v2, v3), oacc[cs], 0, 0, 0);
        }
        __builtin_amdgcn_s_setprio(0);

        __syncthreads();   // drain staged tile t+1; all waves done with buf t
    }

    if (S == 1) {
        const float lr = 1.f / l_run;
        const float l0 = __shfl(lr, 4 * g + 0);
        const float l1 = __shfl(lr, 4 * g + 1);
        const float l2 = __shfl(lr, 4 * g + 2);
        const float l3 = __shfl(lr, 4 * g + 3);
        float* ob = out + (size_t)b * Cn * Nn;
        #pragma unroll
        for (int cs = 0; cs < 8; ++cs) {
            float4 o;
            o.x = oacc[cs][0] * l0;
            o.y = oacc[cs][1] * l1;
            o.z = oacc[cs][2] * l2;
            o.w = oacc[cs][3] * l3;
            *(float4*)&ob[(size_t)(cs * 16 + ln) * Nn + wib + 4 * g] = o;
        }
    } else {
        float* pp = pPart + (((size_t)b * 64 + it) * S + s) * 8192;
        const int qloc = w * 16 + 4 * g;
        #pragma unroll
        for (int cs = 0; cs < 8; ++cs)
            *(float4*)&pp[(size_t)(cs * 16 + ln) * 64 + qloc] =
                make_float4(oacc[cs][0], oacc[cs][1], oacc[cs][2], oacc[cs][3]);
        if (g == 0) {
            float* ml = pMl + ((((size_t)b * 64 + it) * S + s) * 64 + w * 16 + ln) * 2;
            ml[0] = m_run;
            ml[1] = l_run;
        }
    }
}

// ---------------------------------------------------------------------------
// Kernel 3: flash-combine across S splits. Grid (64 it, B), 256 threads.
// ---------------------------------------------------------------------------
__global__ __launch_bounds__(256) void attn_combine(
    const float* __restrict__ pPart, const float* __restrict__ pMl,
    float* __restrict__ out, int S)
{
    const int it  = blockIdx.x;
    const int b   = blockIdx.y;
    const int tid = threadIdx.x;

    __shared__ float wgt[4][64];
    __shared__ float linv[64];

    if (tid < 64) {
        const float* mlb = pMl + (((size_t)b * 64 + it) * S * 64 + tid) * 2;
        float ms[4], ls[4], m = -3.0e38f;
        for (int s = 0; s < S; ++s) {
            ms[s] = mlb[s * 128 + 0];
            ls[s] = mlb[s * 128 + 1];
            m = fmaxf(m, ms[s]);
        }
        float l = 0.f;
        for (int s = 0; s < S; ++s) {
            float wv = __expf(ms[s] - m);
            wgt[s][tid] = wv;
            l += wv * ls[s];
        }
        linv[tid] = 1.f / l;
    }
    __syncthreads();

    const int c  = tid >> 1;
    const int q0 = (tid & 1) * 32;
    const float* base = pPart + ((size_t)b * 64 + it) * S * 8192 + (size_t)c * 64 + q0;

    float acc[32];
    #pragma unroll
    for (int k = 0; k < 32; ++k) acc[k] = 0.f;
    for (int s = 0; s < S; ++s) {
        const float* ps = base + (size_t)s * 8192;
        #pragma unroll
        for (int k = 0; k < 32; k += 4) {
            float4 v = *(const float4*)(ps + k);
            acc[k + 0] += wgt[s][q0 + k + 0] * v.x;
            acc[k + 1] += wgt[s][q0 + k + 1] * v.y;
            acc[k + 2] += wgt[s][q0 + k + 2] * v.z;
            acc[k + 3] += wgt[s][q0 + k + 3] * v.w;
        }
    }
    float* ob = out + ((size_t)b * Cn + c) * Nn + it * 64 + q0;
    #pragma unroll
    for (int k = 0; k < 32; k += 4) {
        float4 o;
        o.x = acc[k + 0] * linv[q0 + k + 0];
        o.y = acc[k + 1] * linv[q0 + k + 1];
        o.z = acc[k + 2] * linv[q0 + k + 2];
        o.w = acc[k + 3] * linv[q0 + k + 3];
        *(float4*)&ob[k] = o;
    }
}

extern "C" void kernel_launch(void* const* d_in, const int* in_sizes, int n_in,
                              void* d_out, int out_size, void* d_ws, size_t ws_size,
                              hipStream_t stream) {
    const float* x  = (const float*)d_in[0];
    const float* Wq = (const float*)d_in[1];
    const float* bq = (const float*)d_in[2];
    const float* Wk = (const float*)d_in[3];
    const float* bk = (const float*)d_in[4];
    const float* Wv = (const float*)d_in[5];
    const float* bv = (const float*)d_in[6];
    float* out = (float*)d_out;

    _Float16* ws = (_Float16*)d_ws;
    _Float16* Qh = ws;
    _Float16* Kh = ws + 1048576;
    _Float16* Vt = ws + 2097152;

    int S = 1;
    if (ws_size >= QKV_BYTES + 4 * (PART_PER_S + ML_PER_S)) S = 4;
    else if (ws_size >= QKV_BYTES + 2 * (PART_PER_S + ML_PER_S)) S = 2;

    float* pPart = (float*)((char*)d_ws + QKV_BYTES);
    float* pMl   = (float*)((char*)d_ws + QKV_BYTES + (size_t)S * PART_PER_S);

    dim3 gproj(Nn / 64, 4, Bn);
    qkv_proj<<<gproj, 256, 0, stream>>>(x, Wq, bq, Wk, bk, Wv, bv, Qh, Kh, Vt);

    dim3 gattn(Nn / 64, Bn, S);
    attn_split<<<gattn, 256, 0, stream>>>(Qh, Kh, Vt, out, pPart, pMl, S);

    if (S > 1) {
        dim3 gcomb(Nn / 64, Bn);
        attn_combine<<<gcomb, 256, 0, stream>>>(pPart, pMl, out, S);
    }
}